// Round 3
// baseline (3318.620 us; speedup 1.0000x reference)
//
#include <hip/hip_runtime.h>
#include <math.h>

// Diffusion sampler: 49 sequential steps, rows independent.
// 256 blocks x 512 threads; each block owns 16 consecutive rows and iterates
// all steps with xy in LDS. All f32 (reference dtype).
// PRNG: exact JAX threefry2x32 in PARTITIONABLE mode (default since 0.4.36):
//   random_bits[j] = w0 ^ w1 of tf(key, (0, j)); split is foldlike.

#define DXY 288
#define HID 256
#define BR 16
#define NTHR 512
#define OUT_Y_OFF 1048576
#define OUT_T_OFF 1179648

typedef unsigned int u32;

__device__ __forceinline__ void tf2x32(u32 k0, u32 k1, u32 x0, u32 x1, u32& o0, u32& o1) {
  u32 ks2 = k0 ^ k1 ^ 0x1BD11BDAu;
#define TFR(r) { x0 += x1; x1 = (x1 << (r)) | (x1 >> (32 - (r))); x1 ^= x0; }
  x0 += k0; x1 += k1;
  TFR(13) TFR(15) TFR(26) TFR(6)
  x0 += k1;  x1 += ks2 + 1u;
  TFR(17) TFR(29) TFR(16) TFR(24)
  x0 += ks2; x1 += k0 + 2u;
  TFR(13) TFR(15) TFR(26) TFR(6)
  x0 += k0;  x1 += k1 + 3u;
  TFR(17) TFR(29) TFR(16) TFR(24)
  x0 += k1;  x1 += ks2 + 4u;
  TFR(13) TFR(15) TFR(26) TFR(6)
  x0 += ks2; x1 += k0 + 5u;
#undef TFR
  o0 = x0; o1 = x1;
}

// partitionable random_bits for flat index j (< 2^32): x0 = 0, x1 = j, out = w0^w1
__device__ __forceinline__ u32 pbits(u32 ka, u32 kb, u32 j) {
  u32 w0, w1;
  tf2x32(ka, kb, 0u, j, w0, w1);
  return w0 ^ w1;
}

__device__ __forceinline__ float u01f(u32 bits) {
  union { u32 i; float f; } v;
  v.i = (bits >> 9) | 0x3F800000u;
  return v.f - 1.0f;
}

// XLA f32 ErfInv (Giles polynomial) - must match jax.random.normal
__device__ __forceinline__ float erfinv32(float x) {
  float w = -log1pf(-x * x);
  float p;
  if (w < 5.0f) {
    w -= 2.5f;
    p = 2.81022636e-08f;
    p = fmaf(p, w, 3.43273939e-07f);
    p = fmaf(p, w, -3.5233877e-06f);
    p = fmaf(p, w, -4.39150654e-06f);
    p = fmaf(p, w, 0.00021858087f);
    p = fmaf(p, w, -0.00125372503f);
    p = fmaf(p, w, -0.00417768164f);
    p = fmaf(p, w, 0.246640727f);
    p = fmaf(p, w, 1.50140941f);
  } else {
    w = sqrtf(w) - 3.0f;
    p = -0.000200214257f;
    p = fmaf(p, w, 0.000100950558f);
    p = fmaf(p, w, 0.00134934322f);
    p = fmaf(p, w, -0.00367342844f);
    p = fmaf(p, w, 0.00573950773f);
    p = fmaf(p, w, -0.0076224613f);
    p = fmaf(p, w, 0.00943887047f);
    p = fmaf(p, w, 1.00167406f);
    p = fmaf(p, w, 2.83297682f);
  }
  return p * x;
}

__device__ __forceinline__ float nrmf(u32 bits) {
  // uniform(lo=nextafter(-1,0), hi=1): span rounds to exactly 2.0f
  float val = fmaf(u01f(bits), 2.0f, -0.99999994f);
  return 1.41421356f * erfinv32(val);
}
__device__ __forceinline__ float gumf(u32 bits) {
  float u = fmaxf(u01f(bits), 1.17549435e-38f);
  return -logf(-logf(u));
}
__device__ __forceinline__ float siluf(float x) {
  return x / (1.0f + expf(-x));
}
__device__ __forceinline__ void fma4(float a, const float4& b, float* acc) {
  acc[0] = fmaf(a, b.x, acc[0]);
  acc[1] = fmaf(a, b.y, acc[1]);
  acc[2] = fmaf(a, b.z, acc[2]);
  acc[3] = fmaf(a, b.w, acc[3]);
}

__global__ __launch_bounds__(NTHR, 2) void sampler_k(
    const float* __restrict__ xy0, const int* __restrict__ t0,
    const float* __restrict__ t_embed,
    const float* __restrict__ tm_w1, const float* __restrict__ tm_b1,
    const float* __restrict__ tm_w2, const float* __restrict__ tm_b2,
    const float* __restrict__ tr_w1, const float* __restrict__ tr_b1,
    const float* __restrict__ tr_w2, const float* __restrict__ tr_b2,
    const float* __restrict__ sh_w, const float* __restrict__ sh_b,
    const float* __restrict__ ch_w, const float* __restrict__ ch_b,
    float* __restrict__ out)
{
  __shared__ float xy_s[BR][DXY];     // 18.4 KB
  __shared__ float h_s[BR][HID];      // 16.4 KB (holds h1 then h2)
  __shared__ float CEs[2][HID];       // te@W1b + b1 (step-independent)
  __shared__ float Cts[2][HID];       // CEs + tm@W1c (per step)
  __shared__ float tmpre_s[HID];
  __shared__ float tmv_s[HID];
  __shared__ float tpart[2][HID];
  __shared__ float logit_s[BR][2];
  __shared__ int tcur[BR];

  const int tid = threadIdx.x;
  const int blk = blockIdx.x;
  const int row0 = blk * BR;          // block owns rows [row0, row0+16)

  for (int idx = tid; idx < BR * DXY; idx += NTHR) {
    int L = idx / DXY;
    int c = idx - L * DXY;
    xy_s[L][c] = xy0[(row0 + L) * DXY + c];
  }
  if (tid < BR) tcur[tid] = t0[row0 + tid];

  // CE[k][c] = b1[c] + sum_i te[k][i]*W1[288+i][c]  (constant over steps)
  {
    const int c = tid & 255;
    const int k = tid >> 8;
    float acc = tr_b1[c];
    for (int i = 0; i < HID; i++)
      acc = fmaf(t_embed[k * HID + i], tr_w1[(288 + i) * HID + c], acc);
    CEs[k][c] = acc;
  }
  __syncthreads();

  #pragma unroll 1
  for (int t_idx = 49; t_idx >= 1; --t_idx) {
    const float tau = (float)t_idx / 50.0f;
    const double lt = 6.214608098422191;  // ln 500
    float sig_t = (float)(0.002 * exp(((double)t_idx / 50.0) * lt));
    float sig_p = (float)(0.002 * exp(((double)(t_idx - 1) / 50.0) * lt));
    const float stepf = sig_t * sig_t - sig_p * sig_p;
    const float sstep = sqrtf(stepf);

    // folded = tf(key(42),(0,t)); foldlike split: k_i = both words of tf(folded,(0,i))
    u32 f0, f1, k1a, k1b, k2a, k2b;
    tf2x32(0u, 42u, 0u, (u32)t_idx, f0, f1);
    tf2x32(f0, f1, 0u, 0u, k1a, k1b);
    tf2x32(f0, f1, 0u, 1u, k2a, k2b);

    // ---- time-mlp and Ct ----
    const int c8 = tid & 255;
    const int kh = tid >> 8;
    if (kh == 0) tmpre_s[c8] = siluf(fmaf(tau, tm_w1[c8], tm_b1[c8]));
    __syncthreads();
    {
      float p = 0.f;
      #pragma unroll 8
      for (int ii = 0; ii < 128; ii++) {
        int i = kh * 128 + ii;
        p = fmaf(tmpre_s[i], tm_w2[i * HID + c8], p);
      }
      tpart[kh][c8] = p;
    }
    __syncthreads();
    if (kh == 0) tmv_s[c8] = tpart[0][c8] + tpart[1][c8] + tm_b2[c8];
    __syncthreads();
    {
      float p = 0.f;
      #pragma unroll 8
      for (int ii = 0; ii < 128; ii++) {
        int i = kh * 128 + ii;
        p = fmaf(tmv_s[i], tr_w1[(544 + i) * HID + c8], p);
      }
      tpart[kh][c8] = p;
    }
    __syncthreads();
    if (kh == 0) {
      float D = tpart[0][c8] + tpart[1][c8];
      Cts[0][c8] = CEs[0][c8] + D;
      Cts[1][c8] = CEs[1][c8] + D;
    }
    __syncthreads();

    // ---- G1: h1 = silu(xy @ W1[0:288] + Ct[t]) ----
    {
      const int cg = tid & 63;
      const int rg = tid >> 6;
      const int c0 = cg * 4;
      const int r0 = rg * 2;
      float acc0[4] = {0.f, 0.f, 0.f, 0.f};
      float acc1[4] = {0.f, 0.f, 0.f, 0.f};
      for (int i = 0; i < DXY; i += 4) {
        float4 va0 = *(const float4*)&xy_s[r0][i];
        float4 va1 = *(const float4*)&xy_s[r0 + 1][i];
        float4 b0 = *(const float4*)(tr_w1 + (i + 0) * HID + c0);
        float4 b1 = *(const float4*)(tr_w1 + (i + 1) * HID + c0);
        float4 b2 = *(const float4*)(tr_w1 + (i + 2) * HID + c0);
        float4 b3 = *(const float4*)(tr_w1 + (i + 3) * HID + c0);
        fma4(va0.x, b0, acc0); fma4(va0.y, b1, acc0); fma4(va0.z, b2, acc0); fma4(va0.w, b3, acc0);
        fma4(va1.x, b0, acc1); fma4(va1.y, b1, acc1); fma4(va1.z, b2, acc1); fma4(va1.w, b3, acc1);
      }
      const int tc0 = tcur[r0], tc1 = tcur[r0 + 1];
      float4 o0, o1;
      o0.x = siluf(acc0[0] + Cts[tc0][c0 + 0]);
      o0.y = siluf(acc0[1] + Cts[tc0][c0 + 1]);
      o0.z = siluf(acc0[2] + Cts[tc0][c0 + 2]);
      o0.w = siluf(acc0[3] + Cts[tc0][c0 + 3]);
      o1.x = siluf(acc1[0] + Cts[tc1][c0 + 0]);
      o1.y = siluf(acc1[1] + Cts[tc1][c0 + 1]);
      o1.z = siluf(acc1[2] + Cts[tc1][c0 + 2]);
      o1.w = siluf(acc1[3] + Cts[tc1][c0 + 3]);
      *(float4*)&h_s[r0][c0] = o0;
      *(float4*)&h_s[r0 + 1][c0] = o1;
    }
    __syncthreads();

    // ---- G2: h2 = silu(h1 @ W2 + b2) ----
    {
      const int cg = tid & 63;
      const int rg = tid >> 6;
      const int c0 = cg * 4;
      const int r0 = rg * 2;
      float acc0[4] = {0.f, 0.f, 0.f, 0.f};
      float acc1[4] = {0.f, 0.f, 0.f, 0.f};
      for (int i = 0; i < HID; i += 4) {
        float4 va0 = *(const float4*)&h_s[r0][i];
        float4 va1 = *(const float4*)&h_s[r0 + 1][i];
        float4 b0 = *(const float4*)(tr_w2 + (i + 0) * HID + c0);
        float4 b1 = *(const float4*)(tr_w2 + (i + 1) * HID + c0);
        float4 b2 = *(const float4*)(tr_w2 + (i + 2) * HID + c0);
        float4 b3 = *(const float4*)(tr_w2 + (i + 3) * HID + c0);
        fma4(va0.x, b0, acc0); fma4(va0.y, b1, acc0); fma4(va0.z, b2, acc0); fma4(va0.w, b3, acc0);
        fma4(va1.x, b0, acc1); fma4(va1.y, b1, acc1); fma4(va1.z, b2, acc1); fma4(va1.w, b3, acc1);
      }
      __syncthreads();  // all h1 reads done before overwrite
      float4 o0, o1;
      o0.x = siluf(acc0[0] + tr_b2[c0 + 0]);
      o0.y = siluf(acc0[1] + tr_b2[c0 + 1]);
      o0.z = siluf(acc0[2] + tr_b2[c0 + 2]);
      o0.w = siluf(acc0[3] + tr_b2[c0 + 3]);
      o1.x = siluf(acc1[0] + tr_b2[c0 + 0]);
      o1.y = siluf(acc1[1] + tr_b2[c0 + 1]);
      o1.z = siluf(acc1[2] + tr_b2[c0 + 2]);
      o1.w = siluf(acc1[3] + tr_b2[c0 + 3]);
      *(float4*)&h_s[r0][c0] = o0;
      *(float4*)&h_s[r0 + 1][c0] = o1;
    }
    __syncthreads();

    // ---- logits partials (h2 @ ch_w) ----
    {
      const int L = tid >> 5;
      const int cch = (tid >> 4) & 1;
      const int kidx = tid & 15;
      float part = 0.f;
      #pragma unroll
      for (int ii = 0; ii < 16; ii++) {
        int i = kidx + 16 * ii;
        part = fmaf(h_s[L][i], ch_w[i * 2 + cch], part);
      }
      #pragma unroll
      for (int off = 8; off > 0; off >>= 1)
        part += __shfl_down(part, off, 16);
      if (kidx == 0) logit_s[L][cch] = part;
    }

    // ---- G3: score = h2 @ sh_w + sh_b; xy += step*score + sqrt(step)*noise ----
    {
      const int rg = tid >> 6;   // rows (rg, rg+8)
      const int cg = tid & 63;   // cols c = cg + 64*u
      float acc30[5] = {0.f, 0.f, 0.f, 0.f, 0.f};
      float acc31[5] = {0.f, 0.f, 0.f, 0.f, 0.f};
      for (int i = 0; i < HID; i += 4) {
        float4 a0 = *(const float4*)&h_s[rg][i];
        float4 a1 = *(const float4*)&h_s[rg + 8][i];
        #pragma unroll
        for (int u = 0; u < 5; u++) {
          if (u == 4 && cg >= 32) continue;
          const float* bp = sh_w + i * DXY + cg + 64 * u;
          float w0 = bp[0];
          float w1 = bp[DXY];
          float w2 = bp[2 * DXY];
          float w3 = bp[3 * DXY];
          acc30[u] = fmaf(a0.x, w0, fmaf(a0.y, w1, fmaf(a0.z, w2, fmaf(a0.w, w3, acc30[u]))));
          acc31[u] = fmaf(a1.x, w0, fmaf(a1.y, w1, fmaf(a1.z, w2, fmaf(a1.w, w3, acc31[u]))));
        }
      }
      const u32 rt = (u32)(row0 + rg);       // top row
      const u32 rb = rt + 8u;                // bottom row
      #pragma unroll
      for (int u = 0; u < 5; u++) {
        if (u == 4 && cg >= 32) continue;
        int c = cg + 64 * u;
        float sb = sh_b[c];
        float sc0 = acc30[u] + sb;
        float sc1 = acc31[u] + sb;
        float n0 = nrmf(pbits(k1a, k1b, rt * 288u + (u32)c));
        float n1 = nrmf(pbits(k1a, k1b, rb * 288u + (u32)c));
        xy_s[rg][c]     = fmaf(sstep, n0, fmaf(stepf, sc0, xy_s[rg][c]));
        xy_s[rg + 8][c] = fmaf(sstep, n1, fmaf(stepf, sc1, xy_s[rg + 8][c]));
      }
    }
    __syncthreads();

    // ---- categorical: t = argmax(logits + gumbel(k2)); gumbel idx = 2r+k ----
    if (tid < 8) {
      const int q = tid;
      float cb0 = ch_b[0], cb1 = ch_b[1];
      float l00 = logit_s[q][0] + cb0;
      float l01 = logit_s[q][1] + cb1;
      float l10 = logit_s[q + 8][0] + cb0;
      float l11 = logit_s[q + 8][1] + cb1;
      u32 ja = (u32)(row0 + q) * 2u;
      u32 jb = (u32)(row0 + q + 8) * 2u;
      float g00 = gumf(pbits(k2a, k2b, ja));
      float g01 = gumf(pbits(k2a, k2b, ja + 1u));
      float g10 = gumf(pbits(k2a, k2b, jb));
      float g11 = gumf(pbits(k2a, k2b, jb + 1u));
      tcur[q]     = (l01 + g01 > l00 + g00) ? 1 : 0;
      tcur[q + 8] = (l11 + g11 > l10 + g10) ? 1 : 0;
    }
    __syncthreads();
  }

  // ---- final store: x (4096x256), y (4096x32), t (4096), all f32 ----
  for (int idx = tid; idx < BR * DXY; idx += NTHR) {
    int L = idx / DXY;
    int c = idx - L * DXY;
    int r = row0 + L;
    float v = xy_s[L][c];
    if (c < 256) out[r * 256 + c] = v;
    else out[OUT_Y_OFF + r * 32 + (c - 256)] = v;
  }
  if (tid < BR) out[OUT_T_OFF + row0 + tid] = (float)tcur[tid];
}

extern "C" void kernel_launch(void* const* d_in, const int* in_sizes, int n_in,
                              void* d_out, int out_size, void* d_ws, size_t ws_size,
                              hipStream_t stream) {
  (void)in_sizes; (void)n_in; (void)d_ws; (void)ws_size; (void)out_size;
  const float* xy0     = (const float*)d_in[0];
  const int*   t0      = (const int*)d_in[1];
  const float* t_embed = (const float*)d_in[2];
  const float* tm_w1   = (const float*)d_in[3];
  const float* tm_b1   = (const float*)d_in[4];
  const float* tm_w2   = (const float*)d_in[5];
  const float* tm_b2   = (const float*)d_in[6];
  const float* tr_w1   = (const float*)d_in[7];
  const float* tr_b1   = (const float*)d_in[8];
  const float* tr_w2   = (const float*)d_in[9];
  const float* tr_b2   = (const float*)d_in[10];
  const float* sh_w    = (const float*)d_in[11];
  const float* sh_b    = (const float*)d_in[12];
  const float* ch_w    = (const float*)d_in[13];
  const float* ch_b    = (const float*)d_in[14];
  float* out = (float*)d_out;

  sampler_k<<<256, NTHR, 0, stream>>>(xy0, t0, t_embed, tm_w1, tm_b1, tm_w2, tm_b2,
                                      tr_w1, tr_b1, tr_w2, tr_b2, sh_w, sh_b,
                                      ch_w, ch_b, out);
}